// Round 1
// baseline (40459.662 us; speedup 1.0000x reference)
//
#include <hip/hip_runtime.h>
#include <hip/hip_bf16.h>
#include <math.h>

#define D_MODEL 768
#define SEQ     197
#define BATCH   32
#define NTOK    (BATCH*SEQ)   // 6304
#define NHEAD   12
#define HDIM    64
#define NEXP    4
#define HID_N   3072
#define DEPTH_N 12

// ---------------- helpers ----------------
static __device__ __forceinline__ float wred_sum(float v){
  #pragma unroll
  for (int off = 32; off; off >>= 1) v += __shfl_down(v, off);
  return v;
}
static __device__ __forceinline__ float wred_max(float v){
  #pragma unroll
  for (int off = 32; off; off >>= 1) v = fmaxf(v, __shfl_down(v, off));
  return v;
}

// ---------------- patch embed (conv 16x16 s16 as per-patch GEMV) ----------------
__global__ __launch_bounds__(256) void patch_embed(const float* __restrict__ x,
                                                   const float* __restrict__ cw,
                                                   const float* __restrict__ cb,
                                                   const float* __restrict__ pos,
                                                   float* __restrict__ xt){
  const int p = blockIdx.x;         // 0..195
  const int b = blockIdx.y;
  const int py = p / 14, px = p % 14;
  const int tid = threadIdx.x;
  __shared__ float patch[768];
  for (int i = tid; i < 768; i += 256){
    int c = i >> 8, rem = i & 255;
    int ky = rem >> 4, kx = rem & 15;
    patch[i] = x[(((size_t)b*3 + c)*224 + py*16 + ky)*224 + px*16 + kx];
  }
  __syncthreads();
  const int n = 1 + p;
  float* orow = xt + ((size_t)b*SEQ + n)*D_MODEL;
  for (int d = tid; d < 768; d += 256){
    const float* wr = cw + (size_t)d*768;
    float acc = 0.f;
    #pragma unroll 8
    for (int k = 0; k < 768; k++) acc += patch[k]*wr[k];
    orow[d] = acc + cb[d] + pos[(size_t)n*D_MODEL + d];
  }
}

__global__ __launch_bounds__(256) void cls_init(const float* __restrict__ cls_tk,
                                                const float* __restrict__ pos,
                                                float* __restrict__ xt){
  const int b = blockIdx.x, tid = threadIdx.x;
  for (int d = tid; d < D_MODEL; d += 256)
    xt[((size_t)b*SEQ)*D_MODEL + d] = cls_tk[d] + pos[d];
}

// ---------------- LayerNorm (row of 768, 256 thr = 3 elems/thr) ----------------
__global__ __launch_bounds__(256) void ln_kernel(const float* __restrict__ x, size_t xstride,
                                                 const float* __restrict__ w,
                                                 const float* __restrict__ b,
                                                 float* __restrict__ y, size_t ystride){
  const int t = blockIdx.x;
  const int tid = threadIdx.x;
  const float* row = x + (size_t)t*xstride;
  float v0 = row[tid], v1 = row[tid+256], v2 = row[tid+512];
  __shared__ float red[4];
  float s = wred_sum(v0+v1+v2);
  if ((tid & 63) == 0) red[tid>>6] = s;
  __syncthreads();
  const float mean = (red[0]+red[1]+red[2]+red[3]) * (1.f/768.f);
  const float d0 = v0-mean, d1 = v1-mean, d2 = v2-mean;
  __syncthreads();
  float q = wred_sum(d0*d0 + d1*d1 + d2*d2);
  if ((tid & 63) == 0) red[tid>>6] = q;
  __syncthreads();
  const float var = (red[0]+red[1]+red[2]+red[3]) * (1.f/768.f);
  const float inv = rsqrtf(var + 1e-5f);
  float* yr = y + (size_t)t*ystride;
  yr[tid]     = d0*inv*w[tid]     + b[tid];
  yr[tid+256] = d1*inv*w[tid+256] + b[tid+256];
  yr[tid+512] = d2*inv*w[tid+512] + b[tid+512];
}

// ---------------- generic GEMM: C[M,N] = A[M,K] @ W[N,K]^T + bias + resid ----------------
__global__ __launch_bounds__(256) void gemm_f32(const float* __restrict__ A,
                                                const float* __restrict__ W,
                                                const float* __restrict__ bias,
                                                const float* __restrict__ resid,
                                                float* __restrict__ C,
                                                int M, int N, int K){
  const int m0 = blockIdx.x*64, bn = blockIdx.y*64;
  const int tid = threadIdx.x;
  const int tx = tid & 15, ty = tid >> 4;
  __shared__ float As[16][65];
  __shared__ float Ws[16][65];
  float acc[4][4] = {};
  for (int k0 = 0; k0 < K; k0 += 16){
    #pragma unroll
    for (int i = 0; i < 4; i++){
      int idx = tid + i*256;
      int k = idx & 15, m = idx >> 4;
      As[k][m] = (m0+m < M) ? A[(size_t)(m0+m)*K + k0 + k] : 0.f;
      Ws[k][m] = (bn+m < N) ? W[(size_t)(bn+m)*K + k0 + k] : 0.f;
    }
    __syncthreads();
    #pragma unroll
    for (int kk = 0; kk < 16; kk++){
      float a0 = As[kk][ty*4+0], a1 = As[kk][ty*4+1], a2 = As[kk][ty*4+2], a3 = As[kk][ty*4+3];
      float w0 = Ws[kk][tx*4+0], w1 = Ws[kk][tx*4+1], w2 = Ws[kk][tx*4+2], w3 = Ws[kk][tx*4+3];
      acc[0][0] += a0*w0; acc[0][1] += a0*w1; acc[0][2] += a0*w2; acc[0][3] += a0*w3;
      acc[1][0] += a1*w0; acc[1][1] += a1*w1; acc[1][2] += a1*w2; acc[1][3] += a1*w3;
      acc[2][0] += a2*w0; acc[2][1] += a2*w1; acc[2][2] += a2*w2; acc[2][3] += a2*w3;
      acc[3][0] += a3*w0; acc[3][1] += a3*w1; acc[3][2] += a3*w2; acc[3][3] += a3*w3;
    }
    __syncthreads();
  }
  #pragma unroll
  for (int i = 0; i < 4; i++){
    int m = m0 + ty*4 + i;
    if (m >= M) continue;
    #pragma unroll
    for (int j = 0; j < 4; j++){
      int n = bn + tx*4 + j;
      if (n >= N) continue;
      float v = acc[i][j];
      if (bias)  v += bias[n];
      if (resid) v += resid[(size_t)m*N + n];
      C[(size_t)m*N + n] = v;
    }
  }
}

// ---------------- attention: one block per (q, h, b) ----------------
__global__ __launch_bounds__(256) void attn_kernel(const float* __restrict__ qkv,
                                                   float* __restrict__ ctx){
  const int qi = blockIdx.x, h = blockIdx.y, b = blockIdx.z;
  const int tid = threadIdx.x;
  __shared__ float qv[64];
  __shared__ float p[SEQ];
  __shared__ float red[4];
  __shared__ float part[4][64];
  const size_t rs = 3*D_MODEL;
  const float* qrow = qkv + ((size_t)(b*SEQ + qi))*rs + h*HDIM;
  if (tid < 64) qv[tid] = qrow[tid] * 0.125f;   // 1/sqrt(64)
  __syncthreads();
  float sc = -3.0e38f;
  if (tid < SEQ){
    const float* krow = qkv + ((size_t)(b*SEQ + tid))*rs + D_MODEL + h*HDIM;
    float acc = 0.f;
    #pragma unroll 8
    for (int d = 0; d < HDIM; d++) acc += qv[d]*krow[d];
    sc = acc;
  }
  float m = wred_max(sc);
  if ((tid & 63) == 0) red[tid>>6] = m;
  __syncthreads();
  m = fmaxf(fmaxf(red[0],red[1]), fmaxf(red[2],red[3]));
  float ex = (tid < SEQ) ? expf(sc - m) : 0.f;
  if (tid < SEQ) p[tid] = ex;
  float s = wred_sum(ex);
  __syncthreads();               // red reuse
  if ((tid & 63) == 0) red[tid>>6] = s;
  __syncthreads();
  const float denom = red[0]+red[1]+red[2]+red[3];
  const int d = tid & 63, g = tid >> 6;
  float acc = 0.f;
  for (int k = g; k < SEQ; k += 4){
    const float* vrow = qkv + ((size_t)(b*SEQ + k))*rs + 2*D_MODEL + h*HDIM;
    acc += p[k]*vrow[d];
  }
  part[g][d] = acc;
  __syncthreads();
  if (tid < 64){
    float r = (part[0][tid]+part[1][tid]+part[2][tid]+part[3][tid]) / denom;
    ctx[((size_t)(b*SEQ + qi))*D_MODEL + h*HDIM + tid] = r;
  }
}

// ---------------- gating + routing ----------------
__global__ __launch_bounds__(256) void gate_kernel(const float* __restrict__ y,
                                                   const float* __restrict__ gw,
                                                   const float* __restrict__ gb,
                                                   int* __restrict__ eidx){
  const int t = blockIdx.x;
  const int tid = threadIdx.x;
  const int e = tid >> 6, lane = tid & 63;
  const float* row = y + (size_t)t*D_MODEL;
  const float* wrow = gw + (size_t)e*D_MODEL;
  float acc = 0.f;
  for (int k = lane; k < D_MODEL; k += 64) acc += row[k]*wrow[k];
  acc = wred_sum(acc);
  __shared__ float sc[NEXP];
  if (lane == 0) sc[e] = acc + gb[e];
  __syncthreads();
  if (tid == 0){
    int best = 0; float bv = sc[0];
    #pragma unroll
    for (int k = 1; k < NEXP; k++) if (sc[k] > bv){ bv = sc[k]; best = k; }
    eidx[t] = best;
  }
}

__global__ void zero_counts(int* c){ if (threadIdx.x < 3*NEXP) c[threadIdx.x] = 0; }

__global__ __launch_bounds__(256) void count_kernel(const int* __restrict__ eidx, int* counts){
  int i = blockIdx.x*256 + threadIdx.x;
  if (i < NTOK) atomicAdd(&counts[eidx[i]], 1);
}

__global__ void offsets_kernel(const int* counts, int* offs, int* cursor){
  if (threadIdx.x == 0){
    int o = 0;
    for (int e = 0; e < NEXP; e++){ offs[e] = o; cursor[e] = o; o += counts[e]; }
  }
}

__global__ __launch_bounds__(256) void scatter_kernel(const int* __restrict__ eidx,
                                                      int* cursor, int* __restrict__ toks){
  int i = blockIdx.x*256 + threadIdx.x;
  if (i < NTOK){ int pos = atomicAdd(&cursor[eidx[i]], 1); toks[pos] = i; }
}

// ---------------- MoE expert GEMMs (gathered rows) ----------------
__global__ __launch_bounds__(256) void moe_e1(const float* __restrict__ y,
                                              const float* __restrict__ e1w,
                                              const float* __restrict__ e1b,
                                              const int* __restrict__ toks,
                                              const int* __restrict__ cnts,
                                              const int* __restrict__ offs,
                                              float* __restrict__ h1){
  const int e = blockIdx.z;
  const int cnt = cnts[e];
  const int m0 = blockIdx.x*64;
  if (m0 >= cnt) return;
  const int base = offs[e];
  const int bn = blockIdx.y*64;                 // < 3072
  const float* W = e1w + (size_t)e*HID_N*D_MODEL;
  const float* bb = e1b + (size_t)e*HID_N;
  const int tid = threadIdx.x;
  const int tx = tid & 15, ty = tid >> 4;
  __shared__ float As[16][65];
  __shared__ float Ws[16][65];
  __shared__ int rowtok[64];
  if (tid < 64) rowtok[tid] = (m0 + tid < cnt) ? toks[base + m0 + tid] : -1;
  __syncthreads();
  float acc[4][4] = {};
  for (int k0 = 0; k0 < D_MODEL; k0 += 16){
    #pragma unroll
    for (int i = 0; i < 4; i++){
      int idx = tid + i*256;
      int k = idx & 15, m = idx >> 4;
      int tok = rowtok[m];
      As[k][m] = (tok >= 0) ? y[(size_t)tok*D_MODEL + k0 + k] : 0.f;
      Ws[k][m] = W[(size_t)(bn+m)*D_MODEL + k0 + k];
    }
    __syncthreads();
    #pragma unroll
    for (int kk = 0; kk < 16; kk++){
      float a0 = As[kk][ty*4+0], a1 = As[kk][ty*4+1], a2 = As[kk][ty*4+2], a3 = As[kk][ty*4+3];
      float w0 = Ws[kk][tx*4+0], w1 = Ws[kk][tx*4+1], w2 = Ws[kk][tx*4+2], w3 = Ws[kk][tx*4+3];
      acc[0][0] += a0*w0; acc[0][1] += a0*w1; acc[0][2] += a0*w2; acc[0][3] += a0*w3;
      acc[1][0] += a1*w0; acc[1][1] += a1*w1; acc[1][2] += a1*w2; acc[1][3] += a1*w3;
      acc[2][0] += a2*w0; acc[2][1] += a2*w1; acc[2][2] += a2*w2; acc[2][3] += a2*w3;
      acc[3][0] += a3*w0; acc[3][1] += a3*w1; acc[3][2] += a3*w2; acc[3][3] += a3*w3;
    }
    __syncthreads();
  }
  #pragma unroll
  for (int i = 0; i < 4; i++){
    int m = ty*4 + i;
    if (m0 + m >= cnt) continue;
    size_t r = (size_t)(base + m0 + m);
    #pragma unroll
    for (int j = 0; j < 4; j++){
      int n = bn + tx*4 + j;
      float v = acc[i][j] + bb[n];
      v = 0.5f*v*(1.f + erff(v*0.70710678118f));   // exact gelu
      h1[r*HID_N + n] = v;
    }
  }
}

__global__ __launch_bounds__(256) void moe_e2(const float* __restrict__ h1,
                                              const float* __restrict__ e2w,
                                              const float* __restrict__ e2b,
                                              const int* __restrict__ toks,
                                              const int* __restrict__ cnts,
                                              const int* __restrict__ offs,
                                              float* __restrict__ xt){
  const int e = blockIdx.z;
  const int cnt = cnts[e];
  const int m0 = blockIdx.x*64;
  if (m0 >= cnt) return;
  const int base = offs[e];
  const int bn = blockIdx.y*64;                 // < 768
  const float* W = e2w + (size_t)e*D_MODEL*HID_N;
  const float* bb = e2b + (size_t)e*D_MODEL;
  const int tid = threadIdx.x;
  const int tx = tid & 15, ty = tid >> 4;
  __shared__ float As[16][65];
  __shared__ float Ws[16][65];
  __shared__ int rowtok[64];
  if (tid < 64) rowtok[tid] = (m0 + tid < cnt) ? toks[base + m0 + tid] : -1;
  __syncthreads();
  float acc[4][4] = {};
  for (int k0 = 0; k0 < HID_N; k0 += 16){
    #pragma unroll
    for (int i = 0; i < 4; i++){
      int idx = tid + i*256;
      int k = idx & 15, m = idx >> 4;
      As[k][m] = (rowtok[m] >= 0) ? h1[(size_t)(base + m0 + m)*HID_N + k0 + k] : 0.f;
      Ws[k][m] = W[(size_t)(bn+m)*HID_N + k0 + k];
    }
    __syncthreads();
    #pragma unroll
    for (int kk = 0; kk < 16; kk++){
      float a0 = As[kk][ty*4+0], a1 = As[kk][ty*4+1], a2 = As[kk][ty*4+2], a3 = As[kk][ty*4+3];
      float w0 = Ws[kk][tx*4+0], w1 = Ws[kk][tx*4+1], w2 = Ws[kk][tx*4+2], w3 = Ws[kk][tx*4+3];
      acc[0][0] += a0*w0; acc[0][1] += a0*w1; acc[0][2] += a0*w2; acc[0][3] += a0*w3;
      acc[1][0] += a1*w0; acc[1][1] += a1*w1; acc[1][2] += a1*w2; acc[1][3] += a1*w3;
      acc[2][0] += a2*w0; acc[2][1] += a2*w1; acc[2][2] += a2*w2; acc[2][3] += a2*w3;
      acc[3][0] += a3*w0; acc[3][1] += a3*w1; acc[3][2] += a3*w2; acc[3][3] += a3*w3;
    }
    __syncthreads();
  }
  #pragma unroll
  for (int i = 0; i < 4; i++){
    int m = ty*4 + i;
    if (m0 + m >= cnt) continue;
    int tok = rowtok[m];
    #pragma unroll
    for (int j = 0; j < 4; j++){
      int n = bn + tx*4 + j;
      xt[(size_t)tok*D_MODEL + n] += acc[i][j] + bb[n];
    }
  }
}

// ---------------- launch ----------------
extern "C" void kernel_launch(void* const* d_in, const int* in_sizes, int n_in,
                              void* d_out, int out_size, void* d_ws, size_t ws_size,
                              hipStream_t stream){
  const float* x      = (const float*)d_in[0];
  const float* conv_w = (const float*)d_in[1];
  const float* conv_b = (const float*)d_in[2];
  const float* cls_tk = (const float*)d_in[3];
  const float* pos    = (const float*)d_in[4];
  const float* ln1w   = (const float*)d_in[5];
  const float* ln1b   = (const float*)d_in[6];
  const float* qkvw   = (const float*)d_in[7];
  const float* qkvb   = (const float*)d_in[8];
  const float* outw   = (const float*)d_in[9];
  const float* outb   = (const float*)d_in[10];
  const float* ln2w   = (const float*)d_in[11];
  const float* ln2b   = (const float*)d_in[12];
  const float* gatew  = (const float*)d_in[13];
  const float* gateb  = (const float*)d_in[14];
  const float* e1w    = (const float*)d_in[15];
  const float* e1b    = (const float*)d_in[16];
  const float* e2w    = (const float*)d_in[17];
  const float* e2b    = (const float*)d_in[18];
  const float* fnw    = (const float*)d_in[19];
  const float* fnb    = (const float*)d_in[20];
  const float* headw  = (const float*)d_in[21];
  const float* headb  = (const float*)d_in[22];
  float* out = (float*)d_out;

  float* ws    = (float*)d_ws;
  float* xt    = ws;                               // NTOK*768
  float* y     = xt  + (size_t)NTOK*D_MODEL;       // NTOK*768
  float* qkv   = y   + (size_t)NTOK*D_MODEL;       // NTOK*2304
  float* ctx   = qkv + (size_t)NTOK*3*D_MODEL;     // NTOK*768
  float* h1    = ctx + (size_t)NTOK*D_MODEL;       // NTOK*3072
  float* clsln = h1  + (size_t)NTOK*HID_N;         // 32*768
  int*   eidx   = (int*)(clsln + (size_t)BATCH*D_MODEL);
  int*   toks   = eidx + NTOK;
  int*   counts = toks + NTOK;
  int*   offs   = counts + NEXP;
  int*   cursor = offs + NEXP;

  dim3 b256(256);
  patch_embed<<<dim3(196, BATCH), b256, 0, stream>>>(x, conv_w, conv_b, pos, xt);
  cls_init<<<dim3(BATCH), b256, 0, stream>>>(cls_tk, pos, xt);

  const int GM = (NTOK + 63)/64;   // 99
  for (int i = 0; i < DEPTH_N; i++){
    ln_kernel<<<dim3(NTOK), b256, 0, stream>>>(xt, D_MODEL,
        ln1w + (size_t)i*D_MODEL, ln1b + (size_t)i*D_MODEL, y, D_MODEL);
    gemm_f32<<<dim3(GM, 36), b256, 0, stream>>>(y,
        qkvw + (size_t)i*3*D_MODEL*D_MODEL, qkvb + (size_t)i*3*D_MODEL,
        nullptr, qkv, NTOK, 3*D_MODEL, D_MODEL);
    attn_kernel<<<dim3(SEQ, NHEAD, BATCH), b256, 0, stream>>>(qkv, ctx);
    gemm_f32<<<dim3(GM, 12), b256, 0, stream>>>(ctx,
        outw + (size_t)i*D_MODEL*D_MODEL, outb + (size_t)i*D_MODEL,
        xt, xt, NTOK, D_MODEL, D_MODEL);
    ln_kernel<<<dim3(NTOK), b256, 0, stream>>>(xt, D_MODEL,
        ln2w + (size_t)i*D_MODEL, ln2b + (size_t)i*D_MODEL, y, D_MODEL);
    gate_kernel<<<dim3(NTOK), b256, 0, stream>>>(y,
        gatew + (size_t)i*NEXP*D_MODEL, gateb + (size_t)i*NEXP, eidx);
    zero_counts<<<1, 64, 0, stream>>>(counts);
    count_kernel<<<dim3((NTOK+255)/256), b256, 0, stream>>>(eidx, counts);
    offsets_kernel<<<1, 64, 0, stream>>>(counts, offs, cursor);
    scatter_kernel<<<dim3((NTOK+255)/256), b256, 0, stream>>>(eidx, cursor, toks);
    moe_e1<<<dim3(GM, HID_N/64, NEXP), b256, 0, stream>>>(y,
        e1w + (size_t)i*NEXP*HID_N*D_MODEL, e1b + (size_t)i*NEXP*HID_N,
        toks, counts, offs, h1);
    moe_e2<<<dim3(GM, D_MODEL/64, NEXP), b256, 0, stream>>>(h1,
        e2w + (size_t)i*NEXP*D_MODEL*HID_N, e2b + (size_t)i*NEXP*D_MODEL,
        toks, counts, offs, xt);
  }

  // final LN on cls rows only, then head
  ln_kernel<<<dim3(BATCH), b256, 0, stream>>>(xt, (size_t)SEQ*D_MODEL, fnw, fnb, clsln, D_MODEL);
  gemm_f32<<<dim3(1, 16), b256, 0, stream>>>(clsln, headw, headb, nullptr, out, BATCH, 1000, D_MODEL);
}

// Round 2
// 15111.156 us; speedup vs baseline: 2.6775x; 2.6775x over previous
//
#include <hip/hip_runtime.h>
#include <hip/hip_bf16.h>
#include <math.h>

#define D_MODEL 768
#define SEQ     197
#define BATCH   32
#define NTOK    (BATCH*SEQ)   // 6304
#define NHEAD   12
#define HDIM    64
#define NEXP    4
#define HID_N   3072
#define DEPTH_N 12

typedef __attribute__((ext_vector_type(4))) float f32x4;
typedef __attribute__((ext_vector_type(8))) short bf16x8;
typedef __attribute__((ext_vector_type(2))) unsigned int u32x2;

// fp32 -> bf16 round-to-nearest-even
static __device__ __forceinline__ unsigned short f2bf(float f){
  unsigned int u = __builtin_bit_cast(unsigned int, f);
  u += 0x7FFFu + ((u >> 16) & 1u);
  return (unsigned short)(u >> 16);
}

static __device__ __forceinline__ float wred_sum(float v){
  #pragma unroll
  for (int off = 32; off; off >>= 1) v += __shfl_down(v, off);
  return v;
}
static __device__ __forceinline__ float wred_max(float v){
  #pragma unroll
  for (int off = 32; off; off >>= 1) v = fmaxf(v, __shfl_down(v, off));
  return v;
}

// =====================================================================
// bf16 MFMA GEMM: C[M,N] = A[M,K] @ W[N,K]^T (+bias +resid +epilogue)
// 128x128 tile, BK=32, 4 waves, each wave 64x64 (4x4 frags of 16x16x32).
// Reg-staged fp32->bf16 conversion into padded LDS ([128][40] bf16).
// MODE 0: C = A@W^T + bias                       (qkv)
// MODE 1: C = A@W^T + bias + resid               (out proj, resid=C=xt)
// MODE 2: gathered A rows (toks), gelu(.+bias)   (moe e1 -> h1 permuted)
// MODE 3: A permuted-contig, scatter-add to C    (moe e2 -> xt)
// MODE 4: A = im2col(x) on the fly, +pos embed   (patch embed -> xt)
// =====================================================================
template<int MODE>
__global__ __launch_bounds__(256, 2) void gemm_bf16(
    const float* __restrict__ A, const float* __restrict__ W,
    const float* __restrict__ bias, const float* __restrict__ resid,
    float* __restrict__ C, const float* __restrict__ pos,
    const int* __restrict__ toks, const int* __restrict__ cnts,
    const int* __restrict__ offs, int M, int N, int K)
{
  const int tid = threadIdx.x;
  int cnt = M, base = 0;
  if (MODE == 2 || MODE == 3){
    cnt  = cnts[blockIdx.z];
    base = offs[blockIdx.z];
    if ((int)blockIdx.x * 128 >= cnt) return;
    W    += (size_t)blockIdx.z * N * K;
    bias += (size_t)blockIdx.z * N;
  }
  const int m0 = blockIdx.x * 128, n0 = blockIdx.y * 128;

  __shared__ __align__(16) unsigned short Asl[2][128][40];
  __shared__ __align__(16) unsigned short Wsl[2][128][40];

  // ---- staging setup: thread (tid>>3) handles row, (tid&7)*4 handles cols
  const int srow = tid >> 3;          // 0..31, +32 per pass
  const int kc   = (tid & 7) * 4;     // 0,4,...,28
  const float* pA[4];
  const float* pW[4];
  size_t pbase4[4];
  #pragma unroll
  for (int p = 0; p < 4; p++){
    int r  = p * 32 + srow;
    int gm = m0 + r;
    if (MODE == 0 || MODE == 1) pA[p] = (gm < M)   ? A + (size_t)gm * K : nullptr;
    if (MODE == 2)              pA[p] = (gm < cnt) ? A + (size_t)toks[base + gm] * K : nullptr;
    if (MODE == 3)              pA[p] = (gm < cnt) ? A + (size_t)(base + gm) * K : nullptr;
    if (MODE == 4){
      int b_ = gm / 196, pp = gm - b_ * 196;
      int py = pp / 14,  px = pp - py * 14;
      pbase4[p] = (size_t)b_ * 150528 + (size_t)py * 3584 + (size_t)px * 16;
      pA[p] = A;
    }
    pW[p] = W + (size_t)(n0 + r) * K;
  }

  const int NT = K >> 5;
  const int lane = tid & 63, wid = tid >> 6;
  const int wr = wid >> 1, wc = wid & 1;
  const int lr = lane & 15, lq = lane >> 4;

  f32x4 acc[4][4] = {};

  auto LOAD = [&](int kt, f32x4* vA, f32x4* vW){
    const int k = kt * 32 + kc;
    #pragma unroll
    for (int p = 0; p < 4; p++){
      if (MODE == 4){
        size_t off = pbase4[p] + (size_t)(k >> 8) * 50176
                   + (size_t)((k >> 4) & 15) * 224 + (size_t)(k & 15);
        vA[p] = *reinterpret_cast<const f32x4*>(A + off);
      } else {
        vA[p] = pA[p] ? *reinterpret_cast<const f32x4*>(pA[p] + k)
                      : f32x4{0.f, 0.f, 0.f, 0.f};
      }
      vW[p] = *reinterpret_cast<const f32x4*>(pW[p] + k);
    }
  };
  auto STORE = [&](int buf, const f32x4* vA, const f32x4* vW){
    #pragma unroll
    for (int p = 0; p < 4; p++){
      int r = p * 32 + srow;
      u32x2 pk;
      pk[0] = (unsigned)f2bf(vA[p][0]) | ((unsigned)f2bf(vA[p][1]) << 16);
      pk[1] = (unsigned)f2bf(vA[p][2]) | ((unsigned)f2bf(vA[p][3]) << 16);
      *reinterpret_cast<u32x2*>(&Asl[buf][r][kc]) = pk;
      pk[0] = (unsigned)f2bf(vW[p][0]) | ((unsigned)f2bf(vW[p][1]) << 16);
      pk[1] = (unsigned)f2bf(vW[p][2]) | ((unsigned)f2bf(vW[p][3]) << 16);
      *reinterpret_cast<u32x2*>(&Wsl[buf][r][kc]) = pk;
    }
  };

  f32x4 cA[4], cW[4];
  LOAD(0, cA, cW);
  STORE(0, cA, cW);
  __syncthreads();

  for (int t = 0; t < NT; t++){
    f32x4 nA[4], nW[4];
    if (t + 1 < NT) LOAD(t + 1, nA, nW);
    const int buf = t & 1;
    bf16x8 af[4], bfr[4];
    #pragma unroll
    for (int mi = 0; mi < 4; mi++)
      af[mi] = *reinterpret_cast<const bf16x8*>(&Asl[buf][wr*64 + mi*16 + lr][lq*8]);
    #pragma unroll
    for (int nj = 0; nj < 4; nj++)
      bfr[nj] = *reinterpret_cast<const bf16x8*>(&Wsl[buf][wc*64 + nj*16 + lr][lq*8]);
    #pragma unroll
    for (int mi = 0; mi < 4; mi++)
      #pragma unroll
      for (int nj = 0; nj < 4; nj++)
        acc[mi][nj] = __builtin_amdgcn_mfma_f32_16x16x32_bf16(af[mi], bfr[nj], acc[mi][nj], 0, 0, 0);
    __syncthreads();
    if (t + 1 < NT){
      STORE((t + 1) & 1, nA, nW);
      __syncthreads();
    }
  }

  // ---- epilogue: C/D layout col=lane&15, row=(lane>>4)*4+reg ----
  #pragma unroll
  for (int nj = 0; nj < 4; nj++){
    const int ncol = n0 + wc*64 + nj*16 + lr;
    const float bv = bias[ncol];
    #pragma unroll
    for (int mi = 0; mi < 4; mi++){
      const int mb = m0 + wr*64 + mi*16 + lq*4;
      #pragma unroll
      for (int j = 0; j < 4; j++){
        const int m = mb + j;
        float v = acc[mi][nj][j] + bv;
        if (MODE == 0){
          if (m < M) C[(size_t)m * N + ncol] = v;
        }
        if (MODE == 1){
          if (m < M) C[(size_t)m * N + ncol] = v + resid[(size_t)m * N + ncol];
        }
        if (MODE == 2){
          if (m < cnt){
            v = 0.5f * v * (1.f + erff(v * 0.70710678118f));
            C[(size_t)(base + m) * N + ncol] = v;
          }
        }
        if (MODE == 3){
          if (m < cnt){
            int tok = toks[base + m];
            C[(size_t)tok * N + ncol] += v;
          }
        }
        if (MODE == 4){
          int b_ = m / 196, pp = m - b_ * 196;
          C[((size_t)b_ * 197 + 1 + pp) * D_MODEL + ncol] =
              v + pos[(size_t)(1 + pp) * D_MODEL + ncol];
        }
      }
    }
  }
}

// ---------------- cls token init ----------------
__global__ __launch_bounds__(256) void cls_init(const float* __restrict__ cls_tk,
                                                const float* __restrict__ pos,
                                                float* __restrict__ xt){
  const int b = blockIdx.x, tid = threadIdx.x;
  for (int d = tid; d < D_MODEL; d += 256)
    xt[((size_t)b*SEQ)*D_MODEL + d] = cls_tk[d] + pos[d];
}

// ---------------- LayerNorm ----------------
__global__ __launch_bounds__(256) void ln_kernel(const float* __restrict__ x, size_t xstride,
                                                 const float* __restrict__ w,
                                                 const float* __restrict__ b,
                                                 float* __restrict__ y, size_t ystride){
  const int t = blockIdx.x;
  const int tid = threadIdx.x;
  const float* row = x + (size_t)t*xstride;
  float v0 = row[tid], v1 = row[tid+256], v2 = row[tid+512];
  __shared__ float red[4];
  float s = wred_sum(v0+v1+v2);
  if ((tid & 63) == 0) red[tid>>6] = s;
  __syncthreads();
  const float mean = (red[0]+red[1]+red[2]+red[3]) * (1.f/768.f);
  const float d0 = v0-mean, d1 = v1-mean, d2 = v2-mean;
  __syncthreads();
  float q = wred_sum(d0*d0 + d1*d1 + d2*d2);
  if ((tid & 63) == 0) red[tid>>6] = q;
  __syncthreads();
  const float var = (red[0]+red[1]+red[2]+red[3]) * (1.f/768.f);
  const float inv = rsqrtf(var + 1e-5f);
  float* yr = y + (size_t)t*ystride;
  yr[tid]     = d0*inv*w[tid]     + b[tid];
  yr[tid+256] = d1*inv*w[tid+256] + b[tid+256];
  yr[tid+512] = d2*inv*w[tid+512] + b[tid+512];
}

// ---------------- attention: one block per (q, h, b) ----------------
__global__ __launch_bounds__(256) void attn_kernel(const float* __restrict__ qkv,
                                                   float* __restrict__ ctx){
  const int qi = blockIdx.x, h = blockIdx.y, b = blockIdx.z;
  const int tid = threadIdx.x;
  __shared__ float qv[64];
  __shared__ float p[SEQ];
  __shared__ float red[4];
  __shared__ float part[4][64];
  const size_t rs = 3*D_MODEL;
  const float* qrow = qkv + ((size_t)(b*SEQ + qi))*rs + h*HDIM;
  if (tid < 64) qv[tid] = qrow[tid] * 0.125f;
  __syncthreads();
  float sc = -3.0e38f;
  if (tid < SEQ){
    const float* krow = qkv + ((size_t)(b*SEQ + tid))*rs + D_MODEL + h*HDIM;
    float acc = 0.f;
    #pragma unroll 8
    for (int d = 0; d < HDIM; d++) acc += qv[d]*krow[d];
    sc = acc;
  }
  float m = wred_max(sc);
  if ((tid & 63) == 0) red[tid>>6] = m;
  __syncthreads();
  m = fmaxf(fmaxf(red[0],red[1]), fmaxf(red[2],red[3]));
  float ex = (tid < SEQ) ? expf(sc - m) : 0.f;
  if (tid < SEQ) p[tid] = ex;
  float s = wred_sum(ex);
  __syncthreads();
  if ((tid & 63) == 0) red[tid>>6] = s;
  __syncthreads();
  const float denom = red[0]+red[1]+red[2]+red[3];
  const int d = tid & 63, g = tid >> 6;
  float acc = 0.f;
  for (int k = g; k < SEQ; k += 4){
    const float* vrow = qkv + ((size_t)(b*SEQ + k))*rs + 2*D_MODEL + h*HDIM;
    acc += p[k]*vrow[d];
  }
  part[g][d] = acc;
  __syncthreads();
  if (tid < 64){
    float r = (part[0][tid]+part[1][tid]+part[2][tid]+part[3][tid]) / denom;
    ctx[((size_t)(b*SEQ + qi))*D_MODEL + h*HDIM + tid] = r;
  }
}

// ---------------- gating + routing ----------------
__global__ __launch_bounds__(256) void gate_kernel(const float* __restrict__ y,
                                                   const float* __restrict__ gw,
                                                   const float* __restrict__ gb,
                                                   int* __restrict__ eidx){
  const int t = blockIdx.x;
  const int tid = threadIdx.x;
  const int e = tid >> 6, lane = tid & 63;
  const float* row = y + (size_t)t*D_MODEL;
  const float* wrow = gw + (size_t)e*D_MODEL;
  float acc = 0.f;
  for (int k = lane; k < D_MODEL; k += 64) acc += row[k]*wrow[k];
  acc = wred_sum(acc);
  __shared__ float sc[NEXP];
  if (lane == 0) sc[e] = acc + gb[e];
  __syncthreads();
  if (tid == 0){
    int best = 0; float bv = sc[0];
    #pragma unroll
    for (int k = 1; k < NEXP; k++) if (sc[k] > bv){ bv = sc[k]; best = k; }
    eidx[t] = best;
  }
}

__global__ void zero_counts(int* c){ if (threadIdx.x < 3*NEXP) c[threadIdx.x] = 0; }

__global__ __launch_bounds__(256) void count_kernel(const int* __restrict__ eidx, int* counts){
  int i = blockIdx.x*256 + threadIdx.x;
  if (i < NTOK) atomicAdd(&counts[eidx[i]], 1);
}

__global__ void offsets_kernel(const int* counts, int* offs, int* cursor){
  if (threadIdx.x == 0){
    int o = 0;
    for (int e = 0; e < NEXP; e++){ offs[e] = o; cursor[e] = o; o += counts[e]; }
  }
}

__global__ __launch_bounds__(256) void scatter_kernel(const int* __restrict__ eidx,
                                                      int* cursor, int* __restrict__ toks){
  int i = blockIdx.x*256 + threadIdx.x;
  if (i < NTOK){ int pos = atomicAdd(&cursor[eidx[i]], 1); toks[pos] = i; }
}

// ---------------- fp32 GEMM kept for the head (final logits precision) ----
__global__ __launch_bounds__(256) void gemm_f32(const float* __restrict__ A,
                                                const float* __restrict__ W,
                                                const float* __restrict__ bias,
                                                const float* __restrict__ resid,
                                                float* __restrict__ C,
                                                int M, int N, int K){
  const int m0 = blockIdx.x*64, bn = blockIdx.y*64;
  const int tid = threadIdx.x;
  const int tx = tid & 15, ty = tid >> 4;
  __shared__ float As[16][65];
  __shared__ float Ws[16][65];
  float acc[4][4] = {};
  for (int k0 = 0; k0 < K; k0 += 16){
    #pragma unroll
    for (int i = 0; i < 4; i++){
      int idx = tid + i*256;
      int k = idx & 15, m = idx >> 4;
      As[k][m] = (m0+m < M) ? A[(size_t)(m0+m)*K + k0 + k] : 0.f;
      Ws[k][m] = (bn+m < N) ? W[(size_t)(bn+m)*K + k0 + k] : 0.f;
    }
    __syncthreads();
    #pragma unroll
    for (int kk = 0; kk < 16; kk++){
      float a0 = As[kk][ty*4+0], a1 = As[kk][ty*4+1], a2 = As[kk][ty*4+2], a3 = As[kk][ty*4+3];
      float w0 = Ws[kk][tx*4+0], w1 = Ws[kk][tx*4+1], w2 = Ws[kk][tx*4+2], w3 = Ws[kk][tx*4+3];
      acc[0][0] += a0*w0; acc[0][1] += a0*w1; acc[0][2] += a0*w2; acc[0][3] += a0*w3;
      acc[1][0] += a1*w0; acc[1][1] += a1*w1; acc[1][2] += a1*w2; acc[1][3] += a1*w3;
      acc[2][0] += a2*w0; acc[2][1] += a2*w1; acc[2][2] += a2*w2; acc[2][3] += a2*w3;
      acc[3][0] += a3*w0; acc[3][1] += a3*w1; acc[3][2] += a3*w2; acc[3][3] += a3*w3;
    }
    __syncthreads();
  }
  #pragma unroll
  for (int i = 0; i < 4; i++){
    int m = m0 + ty*4 + i;
    if (m >= M) continue;
    #pragma unroll
    for (int j = 0; j < 4; j++){
      int n = bn + tx*4 + j;
      if (n >= N) continue;
      float v = acc[i][j];
      if (bias)  v += bias[n];
      if (resid) v += resid[(size_t)m*N + n];
      C[(size_t)m*N + n] = v;
    }
  }
}

// ---------------- launch ----------------
extern "C" void kernel_launch(void* const* d_in, const int* in_sizes, int n_in,
                              void* d_out, int out_size, void* d_ws, size_t ws_size,
                              hipStream_t stream){
  const float* x      = (const float*)d_in[0];
  const float* conv_w = (const float*)d_in[1];
  const float* conv_b = (const float*)d_in[2];
  const float* cls_tk = (const float*)d_in[3];
  const float* pos    = (const float*)d_in[4];
  const float* ln1w   = (const float*)d_in[5];
  const float* ln1b   = (const float*)d_in[6];
  const float* qkvw   = (const float*)d_in[7];
  const float* qkvb   = (const float*)d_in[8];
  const float* outw   = (const float*)d_in[9];
  const float* outb   = (const float*)d_in[10];
  const float* ln2w   = (const float*)d_in[11];
  const float* ln2b   = (const float*)d_in[12];
  const float* gatew  = (const float*)d_in[13];
  const float* gateb  = (const float*)d_in[14];
  const float* e1w    = (const float*)d_in[15];
  const float* e1b    = (const float*)d_in[16];
  const float* e2w    = (const float*)d_in[17];
  const float* e2b    = (const float*)d_in[18];
  const float* fnw    = (const float*)d_in[19];
  const float* fnb    = (const float*)d_in[20];
  const float* headw  = (const float*)d_in[21];
  const float* headb  = (const float*)d_in[22];
  float* out = (float*)d_out;

  float* ws    = (float*)d_ws;
  float* xt    = ws;                               // NTOK*768
  float* y     = xt  + (size_t)NTOK*D_MODEL;       // NTOK*768
  float* qkv   = y   + (size_t)NTOK*D_MODEL;       // NTOK*2304
  float* ctx   = qkv + (size_t)NTOK*3*D_MODEL;     // NTOK*768
  float* h1    = ctx + (size_t)NTOK*D_MODEL;       // NTOK*3072
  float* clsln = h1  + (size_t)NTOK*HID_N;         // 32*768
  int*   eidx   = (int*)(clsln + (size_t)BATCH*D_MODEL);
  int*   toks   = eidx + NTOK;
  int*   counts = toks + NTOK;
  int*   offs   = counts + NEXP;
  int*   cursor = offs + NEXP;

  dim3 b256(256);

  // patch embed as MFMA GEMM (im2col on the fly, pos fused)
  gemm_bf16<4><<<dim3(49, 6), b256, 0, stream>>>(x, conv_w, conv_b, nullptr, xt,
      pos, nullptr, nullptr, nullptr, 6272, D_MODEL, 768);
  cls_init<<<dim3(BATCH), b256, 0, stream>>>(cls_tk, pos, xt);

  for (int i = 0; i < DEPTH_N; i++){
    ln_kernel<<<dim3(NTOK), b256, 0, stream>>>(xt, D_MODEL,
        ln1w + (size_t)i*D_MODEL, ln1b + (size_t)i*D_MODEL, y, D_MODEL);
    gemm_bf16<0><<<dim3(50, 18), b256, 0, stream>>>(y,
        qkvw + (size_t)i*3*D_MODEL*D_MODEL, qkvb + (size_t)i*3*D_MODEL,
        nullptr, qkv, nullptr, nullptr, nullptr, nullptr, NTOK, 3*D_MODEL, D_MODEL);
    attn_kernel<<<dim3(SEQ, NHEAD, BATCH), b256, 0, stream>>>(qkv, ctx);
    gemm_bf16<1><<<dim3(50, 6), b256, 0, stream>>>(ctx,
        outw + (size_t)i*D_MODEL*D_MODEL, outb + (size_t)i*D_MODEL,
        xt, xt, nullptr, nullptr, nullptr, nullptr, NTOK, D_MODEL, D_MODEL);
    ln_kernel<<<dim3(NTOK), b256, 0, stream>>>(xt, D_MODEL,
        ln2w + (size_t)i*D_MODEL, ln2b + (size_t)i*D_MODEL, y, D_MODEL);
    gate_kernel<<<dim3(NTOK), b256, 0, stream>>>(y,
        gatew + (size_t)i*NEXP*D_MODEL, gateb + (size_t)i*NEXP, eidx);
    zero_counts<<<1, 64, 0, stream>>>(counts);
    count_kernel<<<dim3((NTOK+255)/256), b256, 0, stream>>>(eidx, counts);
    offsets_kernel<<<1, 64, 0, stream>>>(counts, offs, cursor);
    scatter_kernel<<<dim3((NTOK+255)/256), b256, 0, stream>>>(eidx, cursor, toks);
    gemm_bf16<2><<<dim3(50, HID_N/128, NEXP), b256, 0, stream>>>(y,
        e1w + (size_t)i*NEXP*HID_N*D_MODEL, e1b + (size_t)i*NEXP*HID_N,
        nullptr, h1, nullptr, toks, counts, offs, NTOK, HID_N, D_MODEL);
    gemm_bf16<3><<<dim3(50, D_MODEL/128, NEXP), b256, 0, stream>>>(h1,
        e2w + (size_t)i*NEXP*D_MODEL*HID_N, e2b + (size_t)i*NEXP*D_MODEL,
        nullptr, xt, nullptr, toks, counts, offs, NTOK, D_MODEL, HID_N);
  }

  ln_kernel<<<dim3(BATCH), b256, 0, stream>>>(xt, (size_t)SEQ*D_MODEL, fnw, fnb, clsln, D_MODEL);
  gemm_f32<<<dim3(1, 16), b256, 0, stream>>>(clsln, headw, headb, nullptr, out, BATCH, 1000, D_MODEL);
}

// Round 5
// 11465.607 us; speedup vs baseline: 3.5288x; 1.3180x over previous
//
#include <hip/hip_runtime.h>
#include <hip/hip_bf16.h>
#include <math.h>

#define D_MODEL 768
#define SEQ     197
#define BATCH   32
#define NTOK    (BATCH*SEQ)   // 6304
#define NHEAD   12
#define HDIM    64
#define NEXP    4
#define HID_N   3072
#define DEPTH_N 12

typedef __attribute__((ext_vector_type(4))) float f32x4;
typedef __attribute__((ext_vector_type(8))) short bf16x8;
typedef __attribute__((ext_vector_type(2))) unsigned int u32x2;

// fp32 -> bf16 round-to-nearest-even
static __device__ __forceinline__ unsigned short f2bf(float f){
  unsigned int u = __builtin_bit_cast(unsigned int, f);
  u += 0x7FFFu + ((u >> 16) & 1u);
  return (unsigned short)(u >> 16);
}
// split x ~= hi + lo (each bf16; 16 mantissa bits total, bf16 exponent range)
static __device__ __forceinline__ void split_bf(float x, unsigned short& h, unsigned short& l){
  h = f2bf(x);
  float hf = __builtin_bit_cast(float, (unsigned)h << 16);
  l = f2bf(x - hf);
}

static __device__ __forceinline__ float wred_sum(float v){
  #pragma unroll
  for (int off = 32; off; off >>= 1) v += __shfl_down(v, off);
  return v;
}

// =====================================================================
// split-precision MFMA GEMM: C = A @ W^T (+bias +resid +epilogue)
// A,W split into hi+lo bf16; D = Ah*Wh + Ah*Wl + Al*Wh (error ~2^-16).
// 128x128 tile, BK=32, 4 waves, single-buffered LDS (40 KB), reg prefetch.
// MODE 0: C = A@W^T + bias                       (qkv)
// MODE 1: C = A@W^T + bias + resid               (out proj)
// MODE 2: gathered A rows (toks), gelu(.+bias)   (moe e1 -> h1 permuted)
// MODE 3: A permuted-contig, scatter-add to C    (moe e2 -> xt)
// MODE 4: A = im2col(x) on the fly, +pos embed   (patch embed -> xt)
// =====================================================================
template<int MODE>
__global__ __launch_bounds__(256, 2) void gemm_bf16x3(
    const float* __restrict__ A, const float* __restrict__ W,
    const float* __restrict__ bias, const float* __restrict__ resid,
    float* __restrict__ C, const float* __restrict__ pos,
    const int* __restrict__ toks, const int* __restrict__ cnts,
    const int* __restrict__ offs, int M, int N, int K)
{
  const int tid = threadIdx.x;
  int cnt = M, base = 0;
  if (MODE == 2 || MODE == 3){
    cnt  = cnts[blockIdx.z];
    base = offs[blockIdx.z];
    if ((int)blockIdx.x * 128 >= cnt) return;
    W    += (size_t)blockIdx.z * N * K;
    bias += (size_t)blockIdx.z * N;
  }
  const int m0 = blockIdx.x * 128, n0 = blockIdx.y * 128;

  __shared__ __align__(16) unsigned short Ah[128][40];
  __shared__ __align__(16) unsigned short Al[128][40];
  __shared__ __align__(16) unsigned short Wh[128][40];
  __shared__ __align__(16) unsigned short Wl[128][40];

  const int srow = tid >> 3;          // 0..31, +32 per pass
  const int kc   = (tid & 7) * 4;     // 0,4,...,28
  const float* pA[4];
  const float* pW[4];
  size_t pbase4[4];
  #pragma unroll
  for (int p = 0; p < 4; p++){
    int r  = p * 32 + srow;
    int gm = m0 + r;
    if (MODE == 0 || MODE == 1) pA[p] = (gm < M)   ? A + (size_t)gm * K : nullptr;
    if (MODE == 2)              pA[p] = (gm < cnt) ? A + (size_t)toks[base + gm] * K : nullptr;
    if (MODE == 3)              pA[p] = (gm < cnt) ? A + (size_t)(base + gm) * K : nullptr;
    if (MODE == 4){
      int b_ = gm / 196, pp = gm - b_ * 196;
      int py = pp / 14,  px = pp - py * 14;
      pbase4[p] = (size_t)b_ * 150528 + (size_t)py * 3584 + (size_t)px * 16;
      pA[p] = A;
    }
    pW[p] = W + (size_t)(n0 + r) * K;
  }

  const int NT = K >> 5;
  const int lane = tid & 63, wid = tid >> 6;
  const int wr = wid >> 1, wc = wid & 1;
  const int lr = lane & 15, lq = lane >> 4;

  f32x4 acc[4][4] = {};

  auto LOAD = [&](int kt, f32x4* vA, f32x4* vW){
    const int k = kt * 32 + kc;
    #pragma unroll
    for (int p = 0; p < 4; p++){
      if (MODE == 4){
        size_t off = pbase4[p] + (size_t)(k >> 8) * 50176
                   + (size_t)((k >> 4) & 15) * 224 + (size_t)(k & 15);
        vA[p] = *reinterpret_cast<const f32x4*>(A + off);
      } else {
        vA[p] = pA[p] ? *reinterpret_cast<const f32x4*>(pA[p] + k)
                      : f32x4{0.f, 0.f, 0.f, 0.f};
      }
      vW[p] = *reinterpret_cast<const f32x4*>(pW[p] + k);
    }
  };
  auto STORE = [&](const f32x4* vA, const f32x4* vW){
    #pragma unroll
    for (int p = 0; p < 4; p++){
      int r = p * 32 + srow;
      unsigned short h0,h1,h2,h3,l0,l1,l2,l3;
      split_bf(vA[p][0], h0, l0); split_bf(vA[p][1], h1, l1);
      split_bf(vA[p][2], h2, l2); split_bf(vA[p][3], h3, l3);
      u32x2 hp, lp;
      hp[0] = (unsigned)h0 | ((unsigned)h1 << 16); hp[1] = (unsigned)h2 | ((unsigned)h3 << 16);
      lp[0] = (unsigned)l0 | ((unsigned)l1 << 16); lp[1] = (unsigned)l2 | ((unsigned)l3 << 16);
      *reinterpret_cast<u32x2*>(&Ah[r][kc]) = hp;
      *reinterpret_cast<u32x2*>(&Al[r][kc]) = lp;
      split_bf(vW[p][0], h0, l0); split_bf(vW[p][1], h1, l1);
      split_bf(vW[p][2], h2, l2); split_bf(vW[p][3], h3, l3);
      hp[0] = (unsigned)h0 | ((unsigned)h1 << 16); hp[1] = (unsigned)h2 | ((unsigned)h3 << 16);
      lp[0] = (unsigned)l0 | ((unsigned)l1 << 16); lp[1] = (unsigned)l2 | ((unsigned)l3 << 16);
      *reinterpret_cast<u32x2*>(&Wh[r][kc]) = hp;
      *reinterpret_cast<u32x2*>(&Wl[r][kc]) = lp;
    }
  };

  {
    f32x4 cA[4], cW[4];
    LOAD(0, cA, cW);
    STORE(cA, cW);
  }
  __syncthreads();

  for (int t = 0; t < NT; t++){
    f32x4 nA[4], nW[4];
    if (t + 1 < NT) LOAD(t + 1, nA, nW);
    bf16x8 afh[4], afl[4], bfh[4], bfl[4];
    #pragma unroll
    for (int mi = 0; mi < 4; mi++){
      afh[mi] = *reinterpret_cast<const bf16x8*>(&Ah[wr*64 + mi*16 + lr][lq*8]);
      afl[mi] = *reinterpret_cast<const bf16x8*>(&Al[wr*64 + mi*16 + lr][lq*8]);
    }
    #pragma unroll
    for (int nj = 0; nj < 4; nj++){
      bfh[nj] = *reinterpret_cast<const bf16x8*>(&Wh[wc*64 + nj*16 + lr][lq*8]);
      bfl[nj] = *reinterpret_cast<const bf16x8*>(&Wl[wc*64 + nj*16 + lr][lq*8]);
    }
    #pragma unroll
    for (int mi = 0; mi < 4; mi++)
      #pragma unroll
      for (int nj = 0; nj < 4; nj++){
        acc[mi][nj] = __builtin_amdgcn_mfma_f32_16x16x32_bf16(afh[mi], bfh[nj], acc[mi][nj], 0, 0, 0);
        acc[mi][nj] = __builtin_amdgcn_mfma_f32_16x16x32_bf16(afh[mi], bfl[nj], acc[mi][nj], 0, 0, 0);
        acc[mi][nj] = __builtin_amdgcn_mfma_f32_16x16x32_bf16(afl[mi], bfh[nj], acc[mi][nj], 0, 0, 0);
      }
    __syncthreads();
    if (t + 1 < NT){
      STORE(nA, nW);
      __syncthreads();
    }
  }

  // ---- epilogue: C/D layout col=lane&15, row=(lane>>4)*4+reg ----
  #pragma unroll
  for (int nj = 0; nj < 4; nj++){
    const int ncol = n0 + wc*64 + nj*16 + lr;
    const float bv = bias[ncol];
    #pragma unroll
    for (int mi = 0; mi < 4; mi++){
      const int mb = m0 + wr*64 + mi*16 + lq*4;
      #pragma unroll
      for (int j = 0; j < 4; j++){
        const int m = mb + j;
        float v = acc[mi][nj][j] + bv;
        if (MODE == 0){
          if (m < M) C[(size_t)m * N + ncol] = v;
        }
        if (MODE == 1){
          if (m < M) C[(size_t)m * N + ncol] = v + resid[(size_t)m * N + ncol];
        }
        if (MODE == 2){
          if (m < cnt){
            v = 0.5f * v * (1.f + erff(v * 0.70710678118f));
            C[(size_t)(base + m) * N + ncol] = v;
          }
        }
        if (MODE == 3){
          if (m < cnt){
            int tok = toks[base + m];
            C[(size_t)tok * N + ncol] += v;
          }
        }
        if (MODE == 4){
          int b_ = m / 196, pp = m - b_ * 196;
          C[((size_t)b_ * 197 + 1 + pp) * D_MODEL + ncol] =
              v + pos[(size_t)(1 + pp) * D_MODEL + ncol];
        }
      }
    }
  }
}

// ---------------- cls token init ----------------
__global__ __launch_bounds__(256) void cls_init(const float* __restrict__ cls_tk,
                                                const float* __restrict__ pos,
                                                float* __restrict__ xt){
  const int b = blockIdx.x, tid = threadIdx.x;
  for (int d = tid; d < D_MODEL; d += 256)
    xt[((size_t)b*SEQ)*D_MODEL + d] = cls_tk[d] + pos[d];
}

// ---------------- LayerNorm ----------------
__global__ __launch_bounds__(256) void ln_kernel(const float* __restrict__ x, size_t xstride,
                                                 const float* __restrict__ w,
                                                 const float* __restrict__ b,
                                                 float* __restrict__ y, size_t ystride){
  const int t = blockIdx.x;
  const int tid = threadIdx.x;
  const float* row = x + (size_t)t*xstride;
  float v0 = row[tid], v1 = row[tid+256], v2 = row[tid+512];
  __shared__ float red[4];
  float s = wred_sum(v0+v1+v2);
  if ((tid & 63) == 0) red[tid>>6] = s;
  __syncthreads();
  const float mean = (red[0]+red[1]+red[2]+red[3]) * (1.f/768.f);
  const float d0 = v0-mean, d1 = v1-mean, d2 = v2-mean;
  __syncthreads();
  float q = wred_sum(d0*d0 + d1*d1 + d2*d2);
  if ((tid & 63) == 0) red[tid>>6] = q;
  __syncthreads();
  const float var = (red[0]+red[1]+red[2]+red[3]) * (1.f/768.f);
  const float inv = rsqrtf(var + 1e-5f);
  float* yr = y + (size_t)t*ystride;
  yr[tid]     = d0*inv*w[tid]     + b[tid];
  yr[tid+256] = d1*inv*w[tid+256] + b[tid+256];
  yr[tid+512] = d2*inv*w[tid+512] + b[tid+512];
}

// =====================================================================
// fp32 flash-style attention (unchanged from round 4)
// =====================================================================
__global__ __launch_bounds__(256, 3) void attn_f32(const float* __restrict__ qkv,
                                                   float* __restrict__ ctx){
  const int qt = blockIdx.x, h = blockIdx.y, b = blockIdx.z;
  const int tid = threadIdx.x;
  const int tx = tid & 15, ty = tid >> 4;
  __shared__ float Qs[64][65];
  __shared__ float KPs[64][65];   // K tile, then reused as P tile
  __shared__ float Vs[64][65];
  const size_t rs = 3*D_MODEL;
  const float* base = qkv + (size_t)b*SEQ*rs + (size_t)h*HDIM;

  #pragma unroll
  for (int it = 0; it < 16; it++){
    int idx = tid + it*256;
    int r = idx >> 6, c = idx & 63;
    int gq = qt*64 + r;
    float v = (gq < SEQ) ? base[(size_t)gq*rs + c] : 0.f;
    Qs[r][c] = v * 0.125f;
  }
  float m_run[4], l_run[4], o[4][4];
  #pragma unroll
  for (int i = 0; i < 4; i++){
    m_run[i] = -3.0e38f; l_run[i] = 0.f;
    #pragma unroll
    for (int j = 0; j < 4; j++) o[i][j] = 0.f;
  }
  __syncthreads();

  for (int kt = 0; kt < 4; kt++){
    #pragma unroll
    for (int it = 0; it < 16; it++){
      int idx = tid + it*256;
      int r = idx >> 6, c = idx & 63;
      int gk = kt*64 + r;
      float kv = (gk < SEQ) ? base[(size_t)gk*rs + D_MODEL   + c] : 0.f;
      float vv = (gk < SEQ) ? base[(size_t)gk*rs + 2*D_MODEL + c] : 0.f;
      KPs[r][c] = kv;
      Vs[r][c]  = vv;
    }
    __syncthreads();
    float s[4][4] = {};
    for (int d = 0; d < 64; d++){
      float qv[4], kv2[4];
      #pragma unroll
      for (int i = 0; i < 4; i++) qv[i]  = Qs[ty*4+i][d];
      #pragma unroll
      for (int j = 0; j < 4; j++) kv2[j] = KPs[tx*4+j][d];
      #pragma unroll
      for (int i = 0; i < 4; i++)
        #pragma unroll
        for (int j = 0; j < 4; j++) s[i][j] += qv[i]*kv2[j];
    }
    #pragma unroll
    for (int j = 0; j < 4; j++){
      if (kt*64 + tx*4 + j >= SEQ){
        #pragma unroll
        for (int i = 0; i < 4; i++) s[i][j] = -3.0e38f;
      }
    }
    float scale[4];
    #pragma unroll
    for (int i = 0; i < 4; i++){
      float mt = fmaxf(fmaxf(s[i][0], s[i][1]), fmaxf(s[i][2], s[i][3]));
      #pragma unroll
      for (int msk = 1; msk <= 8; msk <<= 1) mt = fmaxf(mt, __shfl_xor(mt, msk));
      float mnew = fmaxf(m_run[i], mt);
      scale[i] = __expf(m_run[i] - mnew);
      float ls = 0.f;
      #pragma unroll
      for (int j = 0; j < 4; j++){ s[i][j] = __expf(s[i][j] - mnew); ls += s[i][j]; }
      #pragma unroll
      for (int msk = 1; msk <= 8; msk <<= 1) ls += __shfl_xor(ls, msk);
      l_run[i] = l_run[i]*scale[i] + ls;
      m_run[i] = mnew;
    }
    __syncthreads();
    #pragma unroll
    for (int i = 0; i < 4; i++)
      #pragma unroll
      for (int j = 0; j < 4; j++) KPs[ty*4+i][tx*4+j] = s[i][j];
    __syncthreads();
    #pragma unroll
    for (int i = 0; i < 4; i++)
      #pragma unroll
      for (int j = 0; j < 4; j++) o[i][j] *= scale[i];
    for (int k = 0; k < 64; k++){
      float pv[4], vv[4];
      #pragma unroll
      for (int i = 0; i < 4; i++) pv[i] = KPs[ty*4+i][k];
      #pragma unroll
      for (int j = 0; j < 4; j++) vv[j] = Vs[k][tx*4+j];
      #pragma unroll
      for (int i = 0; i < 4; i++)
        #pragma unroll
        for (int j = 0; j < 4; j++) o[i][j] += pv[i]*vv[j];
    }
    __syncthreads();
  }
  #pragma unroll
  for (int i = 0; i < 4; i++){
    int q = qt*64 + ty*4 + i;
    if (q < SEQ){
      float inv = 1.f / l_run[i];
      #pragma unroll
      for (int j = 0; j < 4; j++)
        ctx[((size_t)(b*SEQ + q))*D_MODEL + h*HDIM + tx*4 + j] = o[i][j]*inv;
    }
  }
}

// ---------------- gating + routing ----------------
__global__ __launch_bounds__(256) void gate_kernel(const float* __restrict__ y,
                                                   const float* __restrict__ gw,
                                                   const float* __restrict__ gb,
                                                   int* __restrict__ eidx){
  const int t = blockIdx.x;
  const int tid = threadIdx.x;
  const int e = tid >> 6, lane = tid & 63;
  const float* row = y + (size_t)t*D_MODEL;
  const float* wrow = gw + (size_t)e*D_MODEL;
  float acc = 0.f;
  for (int k = lane; k < D_MODEL; k += 64) acc += row[k]*wrow[k];
  acc = wred_sum(acc);
  __shared__ float sc[NEXP];
  if (lane == 0) sc[e] = acc + gb[e];
  __syncthreads();
  if (tid == 0){
    int best = 0; float bv = sc[0];
    #pragma unroll
    for (int k = 1; k < NEXP; k++) if (sc[k] > bv){ bv = sc[k]; best = k; }
    eidx[t] = best;
  }
}

__global__ void zero_counts(int* c){ if (threadIdx.x < 3*NEXP) c[threadIdx.x] = 0; }

__global__ __launch_bounds__(256) void count_kernel(const int* __restrict__ eidx, int* counts){
  int i = blockIdx.x*256 + threadIdx.x;
  if (i < NTOK) atomicAdd(&counts[eidx[i]], 1);
}

__global__ void offsets_kernel(const int* counts, int* offs, int* cursor){
  if (threadIdx.x == 0){
    int o = 0;
    for (int e = 0; e < NEXP; e++){ offs[e] = o; cursor[e] = o; o += counts[e]; }
  }
}

__global__ __launch_bounds__(256) void scatter_kernel(const int* __restrict__ eidx,
                                                      int* cursor, int* __restrict__ toks){
  int i = blockIdx.x*256 + threadIdx.x;
  if (i < NTOK){ int pos = atomicAdd(&cursor[eidx[i]], 1); toks[pos] = i; }
}

// ---------------- fp32 GEMM kept for the head ----------------
__global__ __launch_bounds__(256) void gemm_f32(const float* __restrict__ A,
                                                const float* __restrict__ W,
                                                const float* __restrict__ bias,
                                                const float* __restrict__ resid,
                                                float* __restrict__ C,
                                                int M, int N, int K){
  const int m0 = blockIdx.x*64, bn = blockIdx.y*64;
  const int tid = threadIdx.x;
  const int tx = tid & 15, ty = tid >> 4;
  __shared__ float As[16][65];
  __shared__ float Ws[16][65];
  float acc[4][4] = {};
  for (int k0 = 0; k0 < K; k0 += 16){
    #pragma unroll
    for (int i = 0; i < 4; i++){
      int idx = tid + i*256;
      int k = idx & 15, m = idx >> 4;
      As[k][m] = (m0+m < M) ? A[(size_t)(m0+m)*K + k0 + k] : 0.f;
      Ws[k][m] = (bn+m < N) ? W[(size_t)(bn+m)*K + k0 + k] : 0.f;
    }
    __syncthreads();
    #pragma unroll
    for (int kk = 0; kk < 16; kk++){
      float a0 = As[kk][ty*4+0], a1 = As[kk][ty*4+1], a2 = As[kk][ty*4+2], a3 = As[kk][ty*4+3];
      float w0 = Ws[kk][tx*4+0], w1 = Ws[kk][tx*4+1], w2 = Ws[kk][tx*4+2], w3 = Ws[kk][tx*4+3];
      acc[0][0] += a0*w0; acc[0][1] += a0*w1; acc[0][2] += a0*w2; acc[0][3] += a0*w3;
      acc[1][0] += a1*w0; acc[1][1] += a1*w1; acc[1][2] += a1*w2; acc[1][3] += a1*w3;
      acc[2][0] += a2*w0; acc[2][1] += a2*w1; acc[2][2] += a2*w2; acc[2][3] += a2*w3;
      acc[3][0] += a3*w0; acc[3][1] += a3*w1; acc[3][2] += a3*w2; acc[3][3] += a3*w3;
    }
    __syncthreads();
  }
  #pragma unroll
  for (int i = 0; i < 4; i++){
    int m = m0 + ty*4 + i;
    if (m >= M) continue;
    #pragma unroll
    for (int j = 0; j < 4; j++){
      int n = bn + tx*4 + j;
      if (n >= N) continue;
      float v = acc[i][j];
      if (bias)  v += bias[n];
      if (resid) v += resid[(size_t)m*N + n];
      C[(size_t)m*N + n] = v;
    }
  }
}

// ---------------- launch ----------------
extern "C" void kernel_launch(void* const* d_in, const int* in_sizes, int n_in,
                              void* d_out, int out_size, void* d_ws, size_t ws_size,
                              hipStream_t stream){
  const float* x      = (const float*)d_in[0];
  const float* conv_w = (const float*)d_in[1];
  const float* conv_b = (const float*)d_in[2];
  const float* cls_tk = (const float*)d_in[3];
  const float* pos    = (const float*)d_in[4];
  const float* ln1w   = (const float*)d_in[5];
  const float* ln1b   = (const float*)d_in[6];
  const float* qkvw   = (const float*)d_in[7];
  const float* qkvb   = (const float*)d_in[8];
  const float* outw   = (const float*)d_in[9];
  const float* outb   = (const float*)d_in[10];
  const float* ln2w   = (const float*)d_in[11];
  const float* ln2b   = (const float*)d_in[12];
  const float* gatew  = (const float*)d_in[13];
  const float* gateb  = (const float*)d_in[14];
  const float* e1w    = (const float*)d_in[15];
  const float* e1b    = (const float*)d_in[16];
  const float* e2w    = (const float*)d_in[17];
  const float* e2b    = (const float*)d_in[18];
  const float* fnw    = (const float*)d_in[19];
  const float* fnb    = (const float*)d_in[20];
  const float* headw  = (const float*)d_in[21];
  const float* headb  = (const float*)d_in[22];
  float* out = (float*)d_out;

  float* ws    = (float*)d_ws;
  float* xt    = ws;                               // NTOK*768
  float* y     = xt  + (size_t)NTOK*D_MODEL;       // NTOK*768
  float* qkv   = y   + (size_t)NTOK*D_MODEL;       // NTOK*2304
  float* ctx   = qkv + (size_t)NTOK*3*D_MODEL;     // NTOK*768
  float* h1    = ctx + (size_t)NTOK*D_MODEL;       // NTOK*3072
  float* clsln = h1  + (size_t)NTOK*HID_N;         // 32*768
  int*   eidx   = (int*)(clsln + (size_t)BATCH*D_MODEL);
  int*   toks   = eidx + NTOK;
  int*   counts = toks + NTOK;
  int*   offs   = counts + NEXP;
  int*   cursor = offs + NEXP;

  dim3 b256(256);

  gemm_bf16x3<4><<<dim3(49, 6), b256, 0, stream>>>(x, conv_w, conv_b, nullptr, xt,
      pos, nullptr, nullptr, nullptr, 6272, D_MODEL, 768);
  cls_init<<<dim3(BATCH), b256, 0, stream>>>(cls_tk, pos, xt);

  for (int i = 0; i < DEPTH_N; i++){
    ln_kernel<<<dim3(NTOK), b256, 0, stream>>>(xt, D_MODEL,
        ln1w + (size_t)i*D_MODEL, ln1b + (size_t)i*D_MODEL, y, D_MODEL);
    gemm_bf16x3<0><<<dim3(50, 18), b256, 0, stream>>>(y,
        qkvw + (size_t)i*3*D_MODEL*D_MODEL, qkvb + (size_t)i*3*D_MODEL,
        nullptr, qkv, nullptr, nullptr, nullptr, nullptr, NTOK, 3*D_MODEL, D_MODEL);
    attn_f32<<<dim3(4, NHEAD, BATCH), b256, 0, stream>>>(qkv, ctx);
    gemm_bf16x3<1><<<dim3(50, 6), b256, 0, stream>>>(ctx,
        outw + (size_t)i*D_MODEL*D_MODEL, outb + (size_t)i*D_MODEL,
        xt, xt, nullptr, nullptr, nullptr, nullptr, NTOK, D_MODEL, D_MODEL);
    ln_kernel<<<dim3(NTOK), b256, 0, stream>>>(xt, D_MODEL,
        ln2w + (size_t)i*D_MODEL, ln2b + (size_t)i*D_MODEL, y, D_MODEL);
    gate_kernel<<<dim3(NTOK), b256, 0, stream>>>(y,
        gatew + (size_t)i*NEXP*D_MODEL, gateb + (size_t)i*NEXP, eidx);
    zero_counts<<<1, 64, 0, stream>>>(counts);
    count_kernel<<<dim3((NTOK+255)/256), b256, 0, stream>>>(eidx, counts);
    offsets_kernel<<<1, 64, 0, stream>>>(counts, offs, cursor);
    scatter_kernel<<<dim3((NTOK+255)/256), b256, 0, stream>>>(eidx, cursor, toks);
    gemm_bf16x3<2><<<dim3(50, HID_N/128, NEXP), b256, 0, stream>>>(y,
        e1w + (size_t)i*NEXP*HID_N*D_MODEL, e1b + (size_t)i*NEXP*HID_N,
        nullptr, h1, nullptr, toks, counts, offs, NTOK, HID_N, D_MODEL);
    gemm_bf16x3<3><<<dim3(50, D_MODEL/128, NEXP), b256, 0, stream>>>(h1,
        e2w + (size_t)i*NEXP*D_MODEL*HID_N, e2b + (size_t)i*NEXP*D_MODEL,
        nullptr, xt, nullptr, toks, counts, offs, NTOK, D_MODEL, HID_N);
  }

  ln_kernel<<<dim3(BATCH), b256, 0, stream>>>(xt, (size_t)SEQ*D_MODEL, fnw, fnb, clsln, D_MODEL);
  gemm_f32<<<dim3(1, 16), b256, 0, stream>>>(clsln, headw, headb, nullptr, out, BATCH, 1000, D_MODEL);
}

// Round 6
// 11018.063 us; speedup vs baseline: 3.6721x; 1.0406x over previous
//
#include <hip/hip_runtime.h>
#include <hip/hip_bf16.h>
#include <math.h>

#define D_MODEL 768
#define SEQ     197
#define BATCH   32
#define NTOK    (BATCH*SEQ)   // 6304
#define NHEAD   12
#define HDIM    64
#define NEXP    4
#define HID_N   3072
#define DEPTH_N 12

typedef __attribute__((ext_vector_type(4))) float f32x4;
typedef __attribute__((ext_vector_type(8))) short bf16x8;
typedef __attribute__((ext_vector_type(2))) unsigned int u32x2;

// fp32 -> bf16 round-to-nearest-even
static __device__ __forceinline__ unsigned short f2bf(float f){
  unsigned int u = __builtin_bit_cast(unsigned int, f);
  u += 0x7FFFu + ((u >> 16) & 1u);
  return (unsigned short)(u >> 16);
}
// split x ~= hi + lo (each bf16; 16 mantissa bits total, bf16 exponent range)
static __device__ __forceinline__ void split_bf(float x, unsigned short& h, unsigned short& l){
  h = f2bf(x);
  float hf = __builtin_bit_cast(float, (unsigned)h << 16);
  l = f2bf(x - hf);
}

static __device__ __forceinline__ float wred_sum(float v){
  #pragma unroll
  for (int off = 32; off; off >>= 1) v += __shfl_down(v, off);
  return v;
}

// bijective XCD chunk map (m204): hw round-robins blockIdx%8 across XCDs;
// remap so each XCD owns a CONTIGUOUS logical range.
static __device__ __forceinline__ int xcd_map(int orig, int nwg){
  int q = nwg >> 3, r = nwg & 7;
  int xcd = orig & 7, idx = orig >> 3;
  return (xcd < r ? xcd*(q+1) : r*(q+1) + (xcd-r)*q) + idx;
}

// =====================================================================
// split-precision MFMA GEMM: C = A @ W^T (+bias +resid +epilogue)
// A,W split into hi+lo bf16; D = Ah*Wh + Ah*Wl + Al*Wh (error ~2^-16).
// 128x128 tile, BK=32, 4 waves, single-buffered LDS (40 KB), reg prefetch.
// 1D grid, XCD-chunked by-slowest: logical = by*nm + mtile ->
// each XCD chunk = few W panels (L2-resident) x all M tiles.
// MODE 0: C = A@W^T + bias                       (qkv)
// MODE 1: C = A@W^T + bias + resid               (out proj)
// MODE 2: tile-list gathered A rows, gelu        (moe e1 -> h1 permuted)
// MODE 3: tile-list A permuted, scatter-add      (moe e2 -> xt)
// MODE 4: A = im2col(x) on the fly, +pos embed   (patch embed -> xt)
// =====================================================================
template<int MODE>
__global__ __launch_bounds__(256, 2) void gemm_bf16x3(
    const float* __restrict__ A, const float* __restrict__ W,
    const float* __restrict__ bias, const float* __restrict__ resid,
    float* __restrict__ C, const float* __restrict__ pos,
    const int* __restrict__ toks, const int* __restrict__ cnts,
    const int* __restrict__ offs, const int* __restrict__ tiles,
    int M, int N, int K)
{
  const int tid = threadIdx.x;
  const int NB = N >> 7;
  const int nm = gridDim.x / NB;
  const int lg = xcd_map(blockIdx.x, gridDim.x);
  const int mt = lg % nm, nb = lg / nm;

  int cnt = M, base = 0, m0;
  if (MODE == 2 || MODE == 3){
    if (mt >= tiles[0]) return;
    const int e = tiles[1 + 2*mt];
    m0 = tiles[2 + 2*mt];
    cnt  = cnts[e];
    base = offs[e];
    W    += (size_t)e * N * K;
    bias += (size_t)e * N;
  } else {
    m0 = mt * 128;
  }
  const int n0 = nb * 128;

  __shared__ __align__(16) unsigned short Ah[128][40];
  __shared__ __align__(16) unsigned short Al[128][40];
  __shared__ __align__(16) unsigned short Wh[128][40];
  __shared__ __align__(16) unsigned short Wl[128][40];

  const int srow = tid >> 3;          // 0..31, +32 per pass
  const int kc   = (tid & 7) * 4;     // 0,4,...,28
  const float* pA[4];
  const float* pW[4];
  size_t pbase4[4];
  #pragma unroll
  for (int p = 0; p < 4; p++){
    int r  = p * 32 + srow;
    int gm = m0 + r;
    if (MODE == 0 || MODE == 1) pA[p] = (gm < M)   ? A + (size_t)gm * K : nullptr;
    if (MODE == 2)              pA[p] = (gm < cnt) ? A + (size_t)toks[base + gm] * K : nullptr;
    if (MODE == 3)              pA[p] = (gm < cnt) ? A + (size_t)(base + gm) * K : nullptr;
    if (MODE == 4){
      int b_ = gm / 196, pp = gm - b_ * 196;
      int py = pp / 14,  px = pp - py * 14;
      pbase4[p] = (size_t)b_ * 150528 + (size_t)py * 3584 + (size_t)px * 16;
      pA[p] = A;
    }
    pW[p] = W + (size_t)(n0 + r) * K;
  }

  const int NT = K >> 5;
  const int lane = tid & 63, wid = tid >> 6;
  const int wr = wid >> 1, wc = wid & 1;
  const int lr = lane & 15, lq = lane >> 4;

  f32x4 acc[4][4] = {};

  auto LOAD = [&](int kt, f32x4* vA, f32x4* vW){
    const int k = kt * 32 + kc;
    #pragma unroll
    for (int p = 0; p < 4; p++){
      if (MODE == 4){
        size_t off = pbase4[p] + (size_t)(k >> 8) * 50176
                   + (size_t)((k >> 4) & 15) * 224 + (size_t)(k & 15);
        vA[p] = *reinterpret_cast<const f32x4*>(A + off);
      } else {
        vA[p] = pA[p] ? *reinterpret_cast<const f32x4*>(pA[p] + k)
                      : f32x4{0.f, 0.f, 0.f, 0.f};
      }
      vW[p] = *reinterpret_cast<const f32x4*>(pW[p] + k);
    }
  };
  auto STORE = [&](const f32x4* vA, const f32x4* vW){
    #pragma unroll
    for (int p = 0; p < 4; p++){
      int r = p * 32 + srow;
      unsigned short h0,h1,h2,h3,l0,l1,l2,l3;
      split_bf(vA[p][0], h0, l0); split_bf(vA[p][1], h1, l1);
      split_bf(vA[p][2], h2, l2); split_bf(vA[p][3], h3, l3);
      u32x2 hp, lp;
      hp[0] = (unsigned)h0 | ((unsigned)h1 << 16); hp[1] = (unsigned)h2 | ((unsigned)h3 << 16);
      lp[0] = (unsigned)l0 | ((unsigned)l1 << 16); lp[1] = (unsigned)l2 | ((unsigned)l3 << 16);
      *reinterpret_cast<u32x2*>(&Ah[r][kc]) = hp;
      *reinterpret_cast<u32x2*>(&Al[r][kc]) = lp;
      split_bf(vW[p][0], h0, l0); split_bf(vW[p][1], h1, l1);
      split_bf(vW[p][2], h2, l2); split_bf(vW[p][3], h3, l3);
      hp[0] = (unsigned)h0 | ((unsigned)h1 << 16); hp[1] = (unsigned)h2 | ((unsigned)h3 << 16);
      lp[0] = (unsigned)l0 | ((unsigned)l1 << 16); lp[1] = (unsigned)l2 | ((unsigned)l3 << 16);
      *reinterpret_cast<u32x2*>(&Wh[r][kc]) = hp;
      *reinterpret_cast<u32x2*>(&Wl[r][kc]) = lp;
    }
  };

  {
    f32x4 cA[4], cW[4];
    LOAD(0, cA, cW);
    STORE(cA, cW);
  }
  __syncthreads();

  for (int t = 0; t < NT; t++){
    f32x4 nA[4], nW[4];
    if (t + 1 < NT) LOAD(t + 1, nA, nW);
    bf16x8 afh[4], afl[4], bfh[4], bfl[4];
    #pragma unroll
    for (int mi = 0; mi < 4; mi++){
      afh[mi] = *reinterpret_cast<const bf16x8*>(&Ah[wr*64 + mi*16 + lr][lq*8]);
      afl[mi] = *reinterpret_cast<const bf16x8*>(&Al[wr*64 + mi*16 + lr][lq*8]);
    }
    #pragma unroll
    for (int nj = 0; nj < 4; nj++){
      bfh[nj] = *reinterpret_cast<const bf16x8*>(&Wh[wc*64 + nj*16 + lr][lq*8]);
      bfl[nj] = *reinterpret_cast<const bf16x8*>(&Wl[wc*64 + nj*16 + lr][lq*8]);
    }
    #pragma unroll
    for (int mi = 0; mi < 4; mi++)
      #pragma unroll
      for (int nj = 0; nj < 4; nj++){
        acc[mi][nj] = __builtin_amdgcn_mfma_f32_16x16x32_bf16(afh[mi], bfh[nj], acc[mi][nj], 0, 0, 0);
        acc[mi][nj] = __builtin_amdgcn_mfma_f32_16x16x32_bf16(afh[mi], bfl[nj], acc[mi][nj], 0, 0, 0);
        acc[mi][nj] = __builtin_amdgcn_mfma_f32_16x16x32_bf16(afl[mi], bfh[nj], acc[mi][nj], 0, 0, 0);
      }
    __syncthreads();
    if (t + 1 < NT){
      STORE(nA, nW);
      __syncthreads();
    }
  }

  // ---- epilogue: C/D layout col=lane&15, row=(lane>>4)*4+reg ----
  #pragma unroll
  for (int nj = 0; nj < 4; nj++){
    const int ncol = n0 + wc*64 + nj*16 + lr;
    const float bv = bias[ncol];
    #pragma unroll
    for (int mi = 0; mi < 4; mi++){
      const int mb = m0 + wr*64 + mi*16 + lq*4;
      #pragma unroll
      for (int j = 0; j < 4; j++){
        const int m = mb + j;
        float v = acc[mi][nj][j] + bv;
        if (MODE == 0){
          if (m < M) C[(size_t)m * N + ncol] = v;
        }
        if (MODE == 1){
          if (m < M) C[(size_t)m * N + ncol] = v + resid[(size_t)m * N + ncol];
        }
        if (MODE == 2){
          if (m < cnt){
            v = 0.5f * v * (1.f + erff(v * 0.70710678118f));
            C[(size_t)(base + m) * N + ncol] = v;
          }
        }
        if (MODE == 3){
          if (m < cnt){
            int tok = toks[base + m];
            C[(size_t)tok * N + ncol] += v;
          }
        }
        if (MODE == 4){
          int b_ = m / 196, pp = m - b_ * 196;
          C[((size_t)b_ * 197 + 1 + pp) * D_MODEL + ncol] =
              v + pos[(size_t)(1 + pp) * D_MODEL + ncol];
        }
      }
    }
  }
}

// ---------------- cls token init ----------------
__global__ __launch_bounds__(256) void cls_init(const float* __restrict__ cls_tk,
                                                const float* __restrict__ pos,
                                                float* __restrict__ xt){
  const int b = blockIdx.x, tid = threadIdx.x;
  for (int d = tid; d < D_MODEL; d += 256)
    xt[((size_t)b*SEQ)*D_MODEL + d] = cls_tk[d] + pos[d];
}

// ---------------- LayerNorm ----------------
__global__ __launch_bounds__(256) void ln_kernel(const float* __restrict__ x, size_t xstride,
                                                 const float* __restrict__ w,
                                                 const float* __restrict__ b,
                                                 float* __restrict__ y, size_t ystride){
  const int t = blockIdx.x;
  const int tid = threadIdx.x;
  const float* row = x + (size_t)t*xstride;
  float v0 = row[tid], v1 = row[tid+256], v2 = row[tid+512];
  __shared__ float red[4];
  float s = wred_sum(v0+v1+v2);
  if ((tid & 63) == 0) red[tid>>6] = s;
  __syncthreads();
  const float mean = (red[0]+red[1]+red[2]+red[3]) * (1.f/768.f);
  const float d0 = v0-mean, d1 = v1-mean, d2 = v2-mean;
  __syncthreads();
  float q = wred_sum(d0*d0 + d1*d1 + d2*d2);
  if ((tid & 63) == 0) red[tid>>6] = q;
  __syncthreads();
  const float var = (red[0]+red[1]+red[2]+red[3]) * (1.f/768.f);
  const float inv = rsqrtf(var + 1e-5f);
  float* yr = y + (size_t)t*ystride;
  yr[tid]     = d0*inv*w[tid]     + b[tid];
  yr[tid+256] = d1*inv*w[tid+256] + b[tid+256];
  yr[tid+512] = d2*inv*w[tid+512] + b[tid+512];
}

// =====================================================================
// fp32 flash-style attention (unchanged from round 4/5)
// =====================================================================
__global__ __launch_bounds__(256, 3) void attn_f32(const float* __restrict__ qkv,
                                                   float* __restrict__ ctx){
  const int qt = blockIdx.x, h = blockIdx.y, b = blockIdx.z;
  const int tid = threadIdx.x;
  const int tx = tid & 15, ty = tid >> 4;
  __shared__ float Qs[64][65];
  __shared__ float KPs[64][65];   // K tile, then reused as P tile
  __shared__ float Vs[64][65];
  const size_t rs = 3*D_MODEL;
  const float* base = qkv + (size_t)b*SEQ*rs + (size_t)h*HDIM;

  #pragma unroll
  for (int it = 0; it < 16; it++){
    int idx = tid + it*256;
    int r = idx >> 6, c = idx & 63;
    int gq = qt*64 + r;
    float v = (gq < SEQ) ? base[(size_t)gq*rs + c] : 0.f;
    Qs[r][c] = v * 0.125f;
  }
  float m_run[4], l_run[4], o[4][4];
  #pragma unroll
  for (int i = 0; i < 4; i++){
    m_run[i] = -3.0e38f; l_run[i] = 0.f;
    #pragma unroll
    for (int j = 0; j < 4; j++) o[i][j] = 0.f;
  }
  __syncthreads();

  for (int kt = 0; kt < 4; kt++){
    #pragma unroll
    for (int it = 0; it < 16; it++){
      int idx = tid + it*256;
      int r = idx >> 6, c = idx & 63;
      int gk = kt*64 + r;
      float kv = (gk < SEQ) ? base[(size_t)gk*rs + D_MODEL   + c] : 0.f;
      float vv = (gk < SEQ) ? base[(size_t)gk*rs + 2*D_MODEL + c] : 0.f;
      KPs[r][c] = kv;
      Vs[r][c]  = vv;
    }
    __syncthreads();
    float s[4][4] = {};
    for (int d = 0; d < 64; d++){
      float qv[4], kv2[4];
      #pragma unroll
      for (int i = 0; i < 4; i++) qv[i]  = Qs[ty*4+i][d];
      #pragma unroll
      for (int j = 0; j < 4; j++) kv2[j] = KPs[tx*4+j][d];
      #pragma unroll
      for (int i = 0; i < 4; i++)
        #pragma unroll
        for (int j = 0; j < 4; j++) s[i][j] += qv[i]*kv2[j];
    }
    #pragma unroll
    for (int j = 0; j < 4; j++){
      if (kt*64 + tx*4 + j >= SEQ){
        #pragma unroll
        for (int i = 0; i < 4; i++) s[i][j] = -3.0e38f;
      }
    }
    float scale[4];
    #pragma unroll
    for (int i = 0; i < 4; i++){
      float mt = fmaxf(fmaxf(s[i][0], s[i][1]), fmaxf(s[i][2], s[i][3]));
      #pragma unroll
      for (int msk = 1; msk <= 8; msk <<= 1) mt = fmaxf(mt, __shfl_xor(mt, msk));
      float mnew = fmaxf(m_run[i], mt);
      scale[i] = __expf(m_run[i] - mnew);
      float ls = 0.f;
      #pragma unroll
      for (int j = 0; j < 4; j++){ s[i][j] = __expf(s[i][j] - mnew); ls += s[i][j]; }
      #pragma unroll
      for (int msk = 1; msk <= 8; msk <<= 1) ls += __shfl_xor(ls, msk);
      l_run[i] = l_run[i]*scale[i] + ls;
      m_run[i] = mnew;
    }
    __syncthreads();
    #pragma unroll
    for (int i = 0; i < 4; i++)
      #pragma unroll
      for (int j = 0; j < 4; j++) KPs[ty*4+i][tx*4+j] = s[i][j];
    __syncthreads();
    #pragma unroll
    for (int i = 0; i < 4; i++)
      #pragma unroll
      for (int j = 0; j < 4; j++) o[i][j] *= scale[i];
    for (int k = 0; k < 64; k++){
      float pv[4], vv[4];
      #pragma unroll
      for (int i = 0; i < 4; i++) pv[i] = KPs[ty*4+i][k];
      #pragma unroll
      for (int j = 0; j < 4; j++) vv[j] = Vs[k][tx*4+j];
      #pragma unroll
      for (int i = 0; i < 4; i++)
        #pragma unroll
        for (int j = 0; j < 4; j++) o[i][j] += pv[i]*vv[j];
    }
    __syncthreads();
  }
  #pragma unroll
  for (int i = 0; i < 4; i++){
    int q = qt*64 + ty*4 + i;
    if (q < SEQ){
      float inv = 1.f / l_run[i];
      #pragma unroll
      for (int j = 0; j < 4; j++)
        ctx[((size_t)(b*SEQ + q))*D_MODEL + h*HDIM + tx*4 + j] = o[i][j]*inv;
    }
  }
}

// ---------------- gating + routing ----------------
__global__ __launch_bounds__(256) void gate_kernel(const float* __restrict__ y,
                                                   const float* __restrict__ gw,
                                                   const float* __restrict__ gb,
                                                   int* __restrict__ eidx){
  const int t = blockIdx.x;
  const int tid = threadIdx.x;
  const int e = tid >> 6, lane = tid & 63;
  const float* row = y + (size_t)t*D_MODEL;
  const float* wrow = gw + (size_t)e*D_MODEL;
  float acc = 0.f;
  for (int k = lane; k < D_MODEL; k += 64) acc += row[k]*wrow[k];
  acc = wred_sum(acc);
  __shared__ float sc[NEXP];
  if (lane == 0) sc[e] = acc + gb[e];
  __syncthreads();
  if (tid == 0){
    int best = 0; float bv = sc[0];
    #pragma unroll
    for (int k = 1; k < NEXP; k++) if (sc[k] > bv){ bv = sc[k]; best = k; }
    eidx[t] = best;
  }
}

__global__ void zero_counts(int* c){ if (threadIdx.x < 3*NEXP) c[threadIdx.x] = 0; }

__global__ __launch_bounds__(256) void count_kernel(const int* __restrict__ eidx, int* counts){
  int i = blockIdx.x*256 + threadIdx.x;
  if (i < NTOK) atomicAdd(&counts[eidx[i]], 1);
}

// offsets + tile list: tiles[0]=ntiles; tiles[1+2t]=expert, tiles[2+2t]=m0(local)
__global__ void offsets_kernel(const int* counts, int* offs, int* cursor, int* tiles){
  if (threadIdx.x == 0){
    int o = 0, n = 0;
    for (int e = 0; e < NEXP; e++){
      offs[e] = o; cursor[e] = o;
      for (int m0 = 0; m0 < counts[e]; m0 += 128){
        tiles[1+2*n] = e; tiles[2+2*n] = m0; n++;
      }
      o += counts[e];
    }
    tiles[0] = n;
  }
}

__global__ __launch_bounds__(256) void scatter_kernel(const int* __restrict__ eidx,
                                                      int* cursor, int* __restrict__ toks){
  int i = blockIdx.x*256 + threadIdx.x;
  if (i < NTOK){ int pos = atomicAdd(&cursor[eidx[i]], 1); toks[pos] = i; }
}

// ---------------- fp32 GEMM kept for the head ----------------
__global__ __launch_bounds__(256) void gemm_f32(const float* __restrict__ A,
                                                const float* __restrict__ W,
                                                const float* __restrict__ bias,
                                                const float* __restrict__ resid,
                                                float* __restrict__ C,
                                                int M, int N, int K){
  const int m0 = blockIdx.x*64, bn = blockIdx.y*64;
  const int tid = threadIdx.x;
  const int tx = tid & 15, ty = tid >> 4;
  __shared__ float As[16][65];
  __shared__ float Ws[16][65];
  float acc[4][4] = {};
  for (int k0 = 0; k0 < K; k0 += 16){
    #pragma unroll
    for (int i = 0; i < 4; i++){
      int idx = tid + i*256;
      int k = idx & 15, m = idx >> 4;
      As[k][m] = (m0+m < M) ? A[(size_t)(m0+m)*K + k0 + k] : 0.f;
      Ws[k][m] = (bn+m < N) ? W[(size_t)(bn+m)*K + k0 + k] : 0.f;
    }
    __syncthreads();
    #pragma unroll
    for (int kk = 0; kk < 16; kk++){
      float a0 = As[kk][ty*4+0], a1 = As[kk][ty*4+1], a2 = As[kk][ty*4+2], a3 = As[kk][ty*4+3];
      float w0 = Ws[kk][tx*4+0], w1 = Ws[kk][tx*4+1], w2 = Ws[kk][tx*4+2], w3 = Ws[kk][tx*4+3];
      acc[0][0] += a0*w0; acc[0][1] += a0*w1; acc[0][2] += a0*w2; acc[0][3] += a0*w3;
      acc[1][0] += a1*w0; acc[1][1] += a1*w1; acc[1][2] += a1*w2; acc[1][3] += a1*w3;
      acc[2][0] += a2*w0; acc[2][1] += a2*w1; acc[2][2] += a2*w2; acc[2][3] += a2*w3;
      acc[3][0] += a3*w0; acc[3][1] += a3*w1; acc[3][2] += a3*w2; acc[3][3] += a3*w3;
    }
    __syncthreads();
  }
  #pragma unroll
  for (int i = 0; i < 4; i++){
    int m = m0 + ty*4 + i;
    if (m >= M) continue;
    #pragma unroll
    for (int j = 0; j < 4; j++){
      int n = bn + tx*4 + j;
      if (n >= N) continue;
      float v = acc[i][j];
      if (bias)  v += bias[n];
      if (resid) v += resid[(size_t)m*N + n];
      C[(size_t)m*N + n] = v;
    }
  }
}

// ---------------- launch ----------------
extern "C" void kernel_launch(void* const* d_in, const int* in_sizes, int n_in,
                              void* d_out, int out_size, void* d_ws, size_t ws_size,
                              hipStream_t stream){
  const float* x      = (const float*)d_in[0];
  const float* conv_w = (const float*)d_in[1];
  const float* conv_b = (const float*)d_in[2];
  const float* cls_tk = (const float*)d_in[3];
  const float* pos    = (const float*)d_in[4];
  const float* ln1w   = (const float*)d_in[5];
  const float* ln1b   = (const float*)d_in[6];
  const float* qkvw   = (const float*)d_in[7];
  const float* qkvb   = (const float*)d_in[8];
  const float* outw   = (const float*)d_in[9];
  const float* outb   = (const float*)d_in[10];
  const float* ln2w   = (const float*)d_in[11];
  const float* ln2b   = (const float*)d_in[12];
  const float* gatew  = (const float*)d_in[13];
  const float* gateb  = (const float*)d_in[14];
  const float* e1w    = (const float*)d_in[15];
  const float* e1b    = (const float*)d_in[16];
  const float* e2w    = (const float*)d_in[17];
  const float* e2b    = (const float*)d_in[18];
  const float* fnw    = (const float*)d_in[19];
  const float* fnb    = (const float*)d_in[20];
  const float* headw  = (const float*)d_in[21];
  const float* headb  = (const float*)d_in[22];
  float* out = (float*)d_out;

  float* ws    = (float*)d_ws;
  float* xt    = ws;                               // NTOK*768
  float* y     = xt  + (size_t)NTOK*D_MODEL;       // NTOK*768
  float* qkv   = y   + (size_t)NTOK*D_MODEL;       // NTOK*2304
  float* ctx   = qkv + (size_t)NTOK*3*D_MODEL;     // NTOK*768
  float* h1    = ctx + (size_t)NTOK*D_MODEL;       // NTOK*3072
  float* clsln = h1  + (size_t)NTOK*HID_N;         // 32*768
  int*   eidx   = (int*)(clsln + (size_t)BATCH*D_MODEL);
  int*   toks   = eidx + NTOK;
  int*   counts = toks + NTOK;
  int*   offs   = counts + NEXP;
  int*   cursor = offs + NEXP;
  int*   tiles  = cursor + NEXP;                   // 1 + 2*56 ints

  dim3 b256(256);

  // patch embed: nwg = 49 mtiles * 6 nb
  gemm_bf16x3<4><<<dim3(49*6), b256, 0, stream>>>(x, conv_w, conv_b, nullptr, xt,
      pos, nullptr, nullptr, nullptr, nullptr, 6272, D_MODEL, 768);
  cls_init<<<dim3(BATCH), b256, 0, stream>>>(cls_tk, pos, xt);

  for (int i = 0; i < DEPTH_N; i++){
    ln_kernel<<<dim3(NTOK), b256, 0, stream>>>(xt, D_MODEL,
        ln1w + (size_t)i*D_MODEL, ln1b + (size_t)i*D_MODEL, y, D_MODEL);
    gemm_bf16x3<0><<<dim3(50*18), b256, 0, stream>>>(y,
        qkvw + (size_t)i*3*D_MODEL*D_MODEL, qkvb + (size_t)i*3*D_MODEL,
        nullptr, qkv, nullptr, nullptr, nullptr, nullptr, nullptr, NTOK, 3*D_MODEL, D_MODEL);
    attn_f32<<<dim3(4, NHEAD, BATCH), b256, 0, stream>>>(qkv, ctx);
    gemm_bf16x3<1><<<dim3(50*6), b256, 0, stream>>>(ctx,
        outw + (size_t)i*D_MODEL*D_MODEL, outb + (size_t)i*D_MODEL,
        xt, xt, nullptr, nullptr, nullptr, nullptr, nullptr, NTOK, D_MODEL, D_MODEL);
    ln_kernel<<<dim3(NTOK), b256, 0, stream>>>(xt, D_MODEL,
        ln2w + (size_t)i*D_MODEL, ln2b + (size_t)i*D_MODEL, y, D_MODEL);
    gate_kernel<<<dim3(NTOK), b256, 0, stream>>>(y,
        gatew + (size_t)i*NEXP*D_MODEL, gateb + (size_t)i*NEXP, eidx);
    zero_counts<<<1, 64, 0, stream>>>(counts);
    count_kernel<<<dim3((NTOK+255)/256), b256, 0, stream>>>(eidx, counts);
    offsets_kernel<<<1, 64, 0, stream>>>(counts, offs, cursor, tiles);
    scatter_kernel<<<dim3((NTOK+255)/256), b256, 0, stream>>>(eidx, cursor, toks);
    // MoE: 53 max tiles (sum ceil(cnt_e/128) <= 53)
    gemm_bf16x3<2><<<dim3(53*(HID_N/128)), b256, 0, stream>>>(y,
        e1w + (size_t)i*NEXP*HID_N*D_MODEL, e1b + (size_t)i*NEXP*HID_N,
        nullptr, h1, nullptr, toks, counts, offs, tiles, NTOK, HID_N, D_MODEL);
    gemm_bf16x3<3><<<dim3(53*(D_MODEL/128)), b256, 0, stream>>>(h1,
        e2w + (size_t)i*NEXP*D_MODEL*HID_N, e2b + (size_t)i*NEXP*D_MODEL,
        nullptr, xt, nullptr, toks, counts, offs, tiles, NTOK, D_MODEL, HID_N);
  }

  ln_kernel<<<dim3(BATCH), b256, 0, stream>>>(xt, (size_t)SEQ*D_MODEL, fnw, fnb, clsln, D_MODEL);
  gemm_f32<<<dim3(1, 16), b256, 0, stream>>>(clsln, headw, headb, nullptr, out, BATCH, 1000, D_MODEL);
}